// Round 3
// baseline (133.652 us; speedup 1.0000x reference)
//
#include <hip/hip_runtime.h>
#include <hip/hip_cooperative_groups.h>
#include <math.h>

namespace cg = cooperative_groups;

#define LAG 100
#define HID 150
#define NBLK 150   // one block per hidden element

__device__ __forceinline__ float sigmoidf_(float x) {
    return 1.0f / (1.0f + expf(-x));
}

// Single fused cooperative kernel.
// Block b (4 waves) owns gate rows {b, 150+b, 300+b, 450+b} of each layer,
// i.e. ALL FOUR GATES of element b. Wave w computes gate w's row.
//   phase A: layer0 gates -> h1[b] (local cell0)
//   grid.sync()  (cooperative launch -> runtime-guaranteed safe barrier)
//   phase B: layer1 gates -> h2[b] (local cell1)
//   last-arriving block (atomic counter, NO spin) does the output dot.
// Counter is zeroed by block 0 BEFORE grid.sync(), so no memset node is needed
// and the workspace poison cannot corrupt the last-block detection.
// All phase-B operands are prefetched at the top so cold-HBM latency overlaps
// phase A + the grid sync. Math order is identical to the verified 3-kernel
// version (same lane striding, same shuffle trees) for bitwise-equal output.
extern "C" __global__ __launch_bounds__(256, 1)
void k_lstm_coop(const float* __restrict__ x,     // [100]
                 const float* __restrict__ h0,    // [2,150]
                 const float* __restrict__ c0,    // [2,150]
                 const float* __restrict__ Wih0,  // [600,100]
                 const float* __restrict__ Whh0,  // [600,150]
                 const float* __restrict__ bih0,  // [600]
                 const float* __restrict__ bhh0,  // [600]
                 const float* __restrict__ Wih1,  // [600,150]
                 const float* __restrict__ Whh1,  // [600,150]
                 const float* __restrict__ bih1,  // [600]
                 const float* __restrict__ bhh1,  // [600]
                 const float* __restrict__ Wlin,  // [150]
                 const float* __restrict__ blin,  // [1]
                 unsigned*    __restrict__ ctrs,  // [4] ws
                 float*       __restrict__ h1ws,  // [150] ws
                 float*       __restrict__ h2ws,  // [150] ws
                 float*       __restrict__ out)   // [1]
{
    const int b    = blockIdx.x;        // element index 0..149
    const int t    = threadIdx.x;
    const int w    = t >> 6;            // gate index 0..3 (i,f,g,o)
    const int lane = t & 63;
    const int r    = w * HID + b;       // gate row in [0,600)

    __shared__ float sx[LAG];           // x
    __shared__ float sh0[2 * HID];      // h0 both layers
    __shared__ float sh1[HID];          // h1 after barrier
    __shared__ float g0[4], g1[4];
    __shared__ float wsum[4];
    __shared__ int   is_last;

    // ---------- zero the last-block counter before the grid barrier ----------
    if (b == 0 && t == 0)
        __hip_atomic_store(&ctrs[0], 0u, __ATOMIC_RELAXED, __HIP_MEMORY_SCOPE_AGENT);

    // ---------- issue EVERY phase-B cold load up front ----------
    float wiv[3] = {0.f, 0.f, 0.f}, whv[3] = {0.f, 0.f, 0.f};
    {
        const float* __restrict__ wi1 = Wih1 + r * HID;
        const float* __restrict__ wh1 = Whh1 + r * HID;
        #pragma unroll
        for (int j = 0; j < 3; ++j) {
            const int k = lane + 64 * j;
            if (k < HID) { wiv[j] = wi1[k]; whv[j] = wh1[k]; }
        }
    }
    const float b0     = bih0[r] + bhh0[r];
    const float b1     = bih1[r] + bhh1[r];
    const float c0a    = c0[b];                       // cell0 input
    const float c0b    = c0[HID + b];                 // cell1 input
    const float wlin_v = (t < HID) ? Wlin[t] : 0.0f;  // any block may be last
    const float blin_v = blin[0];

    if (t < LAG) sx[t] = x[t];
    for (int k = t; k < 2 * HID; k += 256) sh0[k] = h0[k];
    __syncthreads();

    // ---------- phase A: layer0 gate row r ----------
    float acc = 0.0f;
    {
        const float* __restrict__ wi = Wih0 + r * LAG;
        for (int k = lane; k < LAG; k += 64)
            acc = fmaf(wi[k], sx[k], acc);
        const float* __restrict__ wh = Whh0 + r * HID;
        for (int k = lane; k < HID; k += 64)
            acc = fmaf(wh[k], sh0[k], acc);
    }
    for (int off = 32; off > 0; off >>= 1)
        acc += __shfl_down(acc, off, 64);
    if (lane == 0) g0[w] = acc + b0;
    __syncthreads();                     // g0[0..3] ready

    // ---------- cell0 for element b ----------
    if (t == 0) {
        float i = sigmoidf_(g0[0]);
        float f = sigmoidf_(g0[1]);
        float g = tanhf(g0[2]);
        float o = sigmoidf_(g0[3]);
        float c = fmaf(f, c0a, i * g);
        h1ws[b] = o * tanhf(c);
    }

    // ---------- grid-wide barrier (sanctioned cooperative primitive) ----------
    cg::this_grid().sync();

    if (t < HID) sh1[t] = h1ws[t];
    __syncthreads();

    // ---------- phase B: layer1 gate row r (weights already in registers) ----
    float acc2 = 0.0f;
    #pragma unroll
    for (int j = 0; j < 3; ++j) {
        const int k = lane + 64 * j;
        if (k < HID) {
            acc2 = fmaf(wiv[j], sh1[k], acc2);
            acc2 = fmaf(whv[j], sh0[HID + k], acc2);
        }
    }
    for (int off = 32; off > 0; off >>= 1)
        acc2 += __shfl_down(acc2, off, 64);
    if (lane == 0) g1[w] = acc2 + b1;
    __syncthreads();

    // ---------- cell1 for element b, then last-block detection (NO spin) ----
    if (t == 0) {
        float i = sigmoidf_(g1[0]);
        float f = sigmoidf_(g1[1]);
        float g = tanhf(g1[2]);
        float o = sigmoidf_(g1[3]);
        float c = fmaf(f, c0b, i * g);
        h2ws[b] = o * tanhf(c);
        __threadfence();                 // publish h2[b] device-wide
        unsigned old = __hip_atomic_fetch_add(&ctrs[0], 1u, __ATOMIC_ACQ_REL, __HIP_MEMORY_SCOPE_AGENT);
        is_last = (old == (unsigned)(NBLK - 1));
    }
    __syncthreads();
    if (!is_last) return;

    // ---------- last block: output dot (identical tree to the 3-kernel K3) ----
    float v = 0.0f;
    if (t < HID) v = h2ws[t] * wlin_v;
    for (int off = 32; off > 0; off >>= 1)
        v += __shfl_down(v, off, 64);
    if (lane == 0) wsum[w] = v;
    __syncthreads();
    if (t == 0)
        out[0] = wsum[0] + wsum[1] + wsum[2] + wsum[3] + blin_v;
}

extern "C" void kernel_launch(void* const* d_in, const int* in_sizes, int n_in,
                              void* d_out, int out_size, void* d_ws, size_t ws_size,
                              hipStream_t stream) {
    const float* x    = (const float*)d_in[0];
    const float* h0   = (const float*)d_in[1];
    const float* c0   = (const float*)d_in[2];
    const float* Wih0 = (const float*)d_in[3];
    const float* Whh0 = (const float*)d_in[4];
    const float* bih0 = (const float*)d_in[5];
    const float* bhh0 = (const float*)d_in[6];
    const float* Wih1 = (const float*)d_in[7];
    const float* Whh1 = (const float*)d_in[8];
    const float* bih1 = (const float*)d_in[9];
    const float* bhh1 = (const float*)d_in[10];
    const float* Wlin = (const float*)d_in[11];
    const float* blin = (const float*)d_in[12];
    float* outp = (float*)d_out;

    unsigned* ctrs = (unsigned*)d_ws;            // 16 B of counters
    float*    h1ws = (float*)d_ws + 8;           // +32 B
    float*    h2ws = (float*)d_ws + 8 + 160;     // +672 B

    void* args[] = {
        (void*)&x, (void*)&h0, (void*)&c0,
        (void*)&Wih0, (void*)&Whh0, (void*)&bih0, (void*)&bhh0,
        (void*)&Wih1, (void*)&Whh1, (void*)&bih1, (void*)&bhh1,
        (void*)&Wlin, (void*)&blin,
        (void*)&ctrs, (void*)&h1ws, (void*)&h2ws, (void*)&outp,
    };

    hipLaunchCooperativeKernel((const void*)k_lstm_coop,
                               dim3(NBLK), dim3(256), args, 0, stream);
}

// Round 4
// 88.982 us; speedup vs baseline: 1.5020x; 1.5020x over previous
//
#include <hip/hip_runtime.h>
#include <math.h>

#define LAG 100
#define HID 150
#define G4  (4*HID)   // 600 gate rows per layer
#define NBLK 150

__device__ __forceinline__ float sigmoidf_(float x) {
    return 1.0f / (1.0f + expf(-x));
}

// ---------------- K1: layer0 gates (verified round-0 kernel + ctr zeroing) ----
// 150 blocks x 256 threads; wave w of block blk computes gate row (blk<<2)+w.
extern "C" __global__ __launch_bounds__(256, 1)
void k_gates0(const float* __restrict__ x,     // [100]
              const float* __restrict__ h0,    // [2,150]
              const float* __restrict__ Wih0,  // [600,100]
              const float* __restrict__ Whh0,  // [600,150]
              const float* __restrict__ bih0,  // [600]
              const float* __restrict__ bhh0,  // [600]
              float* __restrict__ sg0,         // [600] out (ws)
              unsigned* __restrict__ ctrs)     // [4] (ws) -> zeroed here for K2
{
    // Zero the last-block counter for K2. Workspace is poisoned between
    // iterations; K1->K2 kernel boundary makes this visible to K2.
    if (blockIdx.x == 0 && threadIdx.x == 0)
        __hip_atomic_store(&ctrs[0], 0u, __ATOMIC_RELAXED, __HIP_MEMORY_SCOPE_AGENT);

    __shared__ float sv[LAG + HID];            // x ++ h0[layer0]
    const int t = threadIdx.x;
    if (t < LAG)            sv[t] = x[t];
    else if (t < LAG + HID) sv[t] = h0[t - LAG];
    __syncthreads();

    const int r    = (blockIdx.x << 2) + (t >> 6);   // 0..599
    const int lane = t & 63;

    float acc = 0.0f;
    const float* __restrict__ wi = Wih0 + r * LAG;
    for (int k = lane; k < LAG; k += 64)
        acc = fmaf(wi[k], sv[k], acc);
    const float* __restrict__ wh = Whh0 + r * HID;
    for (int k = lane; k < HID; k += 64)
        acc = fmaf(wh[k], sv[LAG + k], acc);

    for (int off = 32; off > 0; off >>= 1)
        acc += __shfl_down(acc, off, 64);
    if (lane == 0)
        sg0[r] = acc + bih0[r] + bhh0[r];
}

// ---------------- K2: cell0 + layer1 gates + cell1 + output (last-block) -----
// Block b owns ALL FOUR layer-1 gates of element b: wave w computes gate row
// r = w*150 + b. cell0 is computed redundantly per block (150-wide, as in the
// verified round-0 K2). cell1[b] is then block-local. Each block writes h2[b],
// fetch_adds; the LAST-arriving block runs round-0 K3's reduction verbatim.
// Nobody ever waits -> hang-free under any scheduling.
extern "C" __global__ __launch_bounds__(256, 1)
void k_cell0_gates1_cell1_out(const float* __restrict__ sg0,   // [600] (ws)
                              const float* __restrict__ c0,    // [2,150]
                              const float* __restrict__ h0,    // [2,150]
                              const float* __restrict__ Wih1,  // [600,150]
                              const float* __restrict__ Whh1,  // [600,150]
                              const float* __restrict__ bih1,  // [600]
                              const float* __restrict__ bhh1,  // [600]
                              const float* __restrict__ Wlin,  // [150]
                              const float* __restrict__ blin,  // [1]
                              unsigned* __restrict__ ctrs,     // [4] (ws)
                              float* __restrict__ h2ws,        // [150] (ws)
                              float* __restrict__ out)         // [1]
{
    __shared__ float sh1[HID];    // h1 = layer0 output
    __shared__ float sh01[HID];   // h0[layer1]
    __shared__ float g1s[4];
    __shared__ float wsum[4];
    __shared__ int   is_last;

    const int t    = threadIdx.x;
    const int b    = blockIdx.x;        // element index 0..149
    const int w    = t >> 6;            // gate 0..3 (i,f,g,o)
    const int lane = t & 63;
    const int r    = w * HID + b;       // layer-1 gate row

    // cell0, redundant per block (identical math to verified round-0 K2)
    if (t < HID) {
        float i = sigmoidf_(sg0[t]);
        float f = sigmoidf_(sg0[HID + t]);
        float g = tanhf(sg0[2 * HID + t]);
        float o = sigmoidf_(sg0[3 * HID + t]);
        float c = fmaf(f, c0[t], i * g);
        sh1[t]  = o * tanhf(c);
        sh01[t] = h0[HID + t];
    }
    __syncthreads();

    // layer1 gate row r (same interleaved fma order as verified round-0 K2)
    float acc = 0.0f;
    const float* __restrict__ wi = Wih1 + r * HID;
    const float* __restrict__ wh = Whh1 + r * HID;
    for (int k = lane; k < HID; k += 64) {
        acc = fmaf(wi[k], sh1[k], acc);
        acc = fmaf(wh[k], sh01[k], acc);
    }
    for (int off = 32; off > 0; off >>= 1)
        acc += __shfl_down(acc, off, 64);
    if (lane == 0) g1s[w] = acc + bih1[r] + bhh1[r];
    __syncthreads();

    // cell1 for element b (block-local), publish h2[b], arrive (no waiting)
    if (t == 0) {
        float i = sigmoidf_(g1s[0]);
        float f = sigmoidf_(g1s[1]);
        float g = tanhf(g1s[2]);
        float o = sigmoidf_(g1s[3]);
        float c = fmaf(f, c0[HID + b], i * g);
        h2ws[b] = o * tanhf(c);
        __threadfence();                 // release h2[b] device-wide
        unsigned old = __hip_atomic_fetch_add(&ctrs[0], 1u,
                           __ATOMIC_ACQ_REL, __HIP_MEMORY_SCOPE_AGENT);
        is_last = (old == (unsigned)(NBLK - 1));
    }
    __syncthreads();
    if (!is_last) return;

    // last block: output dot (identical tree to verified round-0 K3)
    float v = 0.0f;
    if (t < HID) {
        float h2 = __hip_atomic_load(&h2ws[t], __ATOMIC_ACQUIRE,
                                     __HIP_MEMORY_SCOPE_AGENT);
        v = h2 * Wlin[t];
    }
    for (int off = 32; off > 0; off >>= 1)
        v += __shfl_down(v, off, 64);
    if (lane == 0) wsum[w] = v;
    __syncthreads();
    if (t == 0)
        out[0] = wsum[0] + wsum[1] + wsum[2] + wsum[3] + blin[0];
}

extern "C" void kernel_launch(void* const* d_in, const int* in_sizes, int n_in,
                              void* d_out, int out_size, void* d_ws, size_t ws_size,
                              hipStream_t stream) {
    const float* x    = (const float*)d_in[0];
    const float* h0   = (const float*)d_in[1];
    const float* c0   = (const float*)d_in[2];
    const float* Wih0 = (const float*)d_in[3];
    const float* Whh0 = (const float*)d_in[4];
    const float* bih0 = (const float*)d_in[5];
    const float* bhh0 = (const float*)d_in[6];
    const float* Wih1 = (const float*)d_in[7];
    const float* Whh1 = (const float*)d_in[8];
    const float* bih1 = (const float*)d_in[9];
    const float* bhh1 = (const float*)d_in[10];
    const float* Wlin = (const float*)d_in[11];
    const float* blin = (const float*)d_in[12];
    float* outp = (float*)d_out;

    unsigned* ctrs = (unsigned*)d_ws;                 // 16 B counters
    float*    sg0  = (float*)d_ws + 4;                // [600]
    float*    h2ws = (float*)d_ws + 4 + G4;           // [150]

    k_gates0<<<NBLK, 256, 0, stream>>>(x, h0, Wih0, Whh0, bih0, bhh0, sg0, ctrs);
    k_cell0_gates1_cell1_out<<<NBLK, 256, 0, stream>>>(sg0, c0, h0,
                                                       Wih1, Whh1, bih1, bhh1,
                                                       Wlin, blin, ctrs, h2ws, outp);
}

// Round 5
// 83.982 us; speedup vs baseline: 1.5914x; 1.0595x over previous
//
#include <hip/hip_runtime.h>
#include <math.h>

#define LAG 100
#define HID 150
#define G4  (4*HID)   // 600 gate rows per layer

__device__ __forceinline__ float sigmoidf_(float x) {
    return 1.0f / (1.0f + expf(-x));
}

// ---------------- K1: layer0 gates ----------------
// 150 blocks x 256 threads; wave w computes gate row (blk<<2)+w.
// Weight-row + bias loads are HOISTED to the kernel top so their cold-HBM
// latency (workspace poison evicts L2+L3 every iteration) overlaps the
// x/h0 LDS staging + barrier. The fmaf sequence below is unrolled in the
// EXACT order/association of the verified round-0 kernel -> bitwise-equal.
extern "C" __global__ __launch_bounds__(256, 1)
void k_gates0(const float* __restrict__ x,     // [100]
              const float* __restrict__ h0,    // [2,150]
              const float* __restrict__ Wih0,  // [600,100]
              const float* __restrict__ Whh0,  // [600,150]
              const float* __restrict__ bih0,  // [600]
              const float* __restrict__ bhh0,  // [600]
              float* __restrict__ sg0)         // [600] out (ws)
{
    __shared__ float sv[LAG + HID];            // x ++ h0[layer0]
    const int t    = threadIdx.x;
    const int r    = (blockIdx.x << 2) + (t >> 6);   // 0..599
    const int lane = t & 63;

    // ---- hoisted cold loads (issue before staging; overlap with barrier) ----
    const float* __restrict__ wi = Wih0 + r * LAG;
    const float* __restrict__ wh = Whh0 + r * HID;
    const float wiv0 = wi[lane];                                   // k=lane (<100 always)
    const float wiv1 = (lane < LAG - 64) ? wi[lane + 64] : 0.0f;   // k=lane+64
    const float whv0 = wh[lane];                                   // k=lane
    const float whv1 = wh[lane + 64];                              // k=lane+64 (<150 always)
    const float whv2 = (lane < HID - 128) ? wh[lane + 128] : 0.0f; // k=lane+128
    const float rb0  = bih0[r];
    const float rb1  = bhh0[r];

    if (t < LAG)            sv[t] = x[t];
    else if (t < LAG + HID) sv[t] = h0[t - LAG];
    __syncthreads();

    // ---- fmaf chain: identical order to round-0 loops ----
    float acc = 0.0f;
    acc = fmaf(wiv0, sv[lane], acc);
    if (lane < LAG - 64)  acc = fmaf(wiv1, sv[lane + 64], acc);
    acc = fmaf(whv0, sv[LAG + lane], acc);
    acc = fmaf(whv1, sv[LAG + lane + 64], acc);
    if (lane < HID - 128) acc = fmaf(whv2, sv[LAG + lane + 128], acc);

    for (int off = 32; off > 0; off >>= 1)
        acc += __shfl_down(acc, off, 64);
    if (lane == 0)
        sg0[r] = acc + rb0 + rb1;
}

// ---------------- K2: cell0 (redundant per block) + layer1 gates ----------------
// Weight rows hoisted to kernel top: cold-HBM fetch overlaps the cell0
// transcendental chain (4x exp/tanh) + barrier. fmaf order identical to R0.
extern "C" __global__ __launch_bounds__(256, 1)
void k_cell0_gates1(const float* __restrict__ sg0,   // [600] (ws, L2-hot)
                    const float* __restrict__ c0,    // [2,150]
                    const float* __restrict__ h0,    // [2,150]
                    const float* __restrict__ Wih1,  // [600,150]
                    const float* __restrict__ Whh1,  // [600,150]
                    const float* __restrict__ bih1,  // [600]
                    const float* __restrict__ bhh1,  // [600]
                    float* __restrict__ sg1)         // [600] out (ws)
{
    __shared__ float sh1[HID];    // h1 = layer0 output
    __shared__ float sh01[HID];   // h0[layer1]
    const int t    = threadIdx.x;
    const int r    = (blockIdx.x << 2) + (t >> 6);   // 0..599
    const int lane = t & 63;

    // ---- hoisted cold loads ----
    const float* __restrict__ wi = Wih1 + r * HID;
    const float* __restrict__ wh = Whh1 + r * HID;
    const float wiv0 = wi[lane];
    const float wiv1 = wi[lane + 64];
    const float wiv2 = (lane < HID - 128) ? wi[lane + 128] : 0.0f;
    const float whv0 = wh[lane];
    const float whv1 = wh[lane + 64];
    const float whv2 = (lane < HID - 128) ? wh[lane + 128] : 0.0f;
    const float rb0  = bih1[r];
    const float rb1  = bhh1[r];

    // ---- cell0, identical math to round-0 ----
    if (t < HID) {
        float i = sigmoidf_(sg0[t]);
        float f = sigmoidf_(sg0[HID + t]);
        float g = tanhf(sg0[2 * HID + t]);
        float o = sigmoidf_(sg0[3 * HID + t]);
        float c = fmaf(f, c0[t], i * g);
        sh1[t]  = o * tanhf(c);
        sh01[t] = h0[HID + t];
    }
    __syncthreads();

    // ---- fmaf chain: identical interleaved order to round-0 loop ----
    float acc = 0.0f;
    acc = fmaf(wiv0, sh1[lane], acc);
    acc = fmaf(whv0, sh01[lane], acc);
    acc = fmaf(wiv1, sh1[lane + 64], acc);
    acc = fmaf(whv1, sh01[lane + 64], acc);
    if (lane < HID - 128) {
        acc = fmaf(wiv2, sh1[lane + 128], acc);
        acc = fmaf(whv2, sh01[lane + 128], acc);
    }

    for (int off = 32; off > 0; off >>= 1)
        acc += __shfl_down(acc, off, 64);
    if (lane == 0)
        sg1[r] = acc + rb0 + rb1;
}

// ---------------- K3: cell1 + linear (verbatim round-0) ----------------
extern "C" __global__ __launch_bounds__(256, 1)
void k_cell1_out(const float* __restrict__ sg1,   // [600] (ws, L2-hot)
                 const float* __restrict__ c0,    // [2,150]
                 const float* __restrict__ Wlin,  // [150]
                 const float* __restrict__ blin,  // [1]
                 float* __restrict__ out)         // [1]
{
    const int t = threadIdx.x;
    float v = 0.0f;
    if (t < HID) {
        float i = sigmoidf_(sg1[t]);
        float f = sigmoidf_(sg1[HID + t]);
        float g = tanhf(sg1[2 * HID + t]);
        float o = sigmoidf_(sg1[3 * HID + t]);
        float c = fmaf(f, c0[HID + t], i * g);
        v = o * tanhf(c) * Wlin[t];
    }
    for (int off = 32; off > 0; off >>= 1)
        v += __shfl_down(v, off, 64);

    __shared__ float wsum[4];
    if ((t & 63) == 0) wsum[t >> 6] = v;
    __syncthreads();
    if (t == 0)
        out[0] = wsum[0] + wsum[1] + wsum[2] + wsum[3] + blin[0];
}

extern "C" void kernel_launch(void* const* d_in, const int* in_sizes, int n_in,
                              void* d_out, int out_size, void* d_ws, size_t ws_size,
                              hipStream_t stream) {
    const float* x    = (const float*)d_in[0];
    const float* h0   = (const float*)d_in[1];
    const float* c0   = (const float*)d_in[2];
    const float* Wih0 = (const float*)d_in[3];
    const float* Whh0 = (const float*)d_in[4];
    const float* bih0 = (const float*)d_in[5];
    const float* bhh0 = (const float*)d_in[6];
    const float* Wih1 = (const float*)d_in[7];
    const float* Whh1 = (const float*)d_in[8];
    const float* bih1 = (const float*)d_in[9];
    const float* bhh1 = (const float*)d_in[10];
    const float* Wlin = (const float*)d_in[11];
    const float* blin = (const float*)d_in[12];
    float* out = (float*)d_out;

    float* sg0 = (float*)d_ws;          // [600]
    float* sg1 = sg0 + G4;              // [600]

    k_gates0<<<150, 256, 0, stream>>>(x, h0, Wih0, Whh0, bih0, bhh0, sg0);
    k_cell0_gates1<<<150, 256, 0, stream>>>(sg0, c0, h0, Wih1, Whh1, bih1, bhh1, sg1);
    k_cell1_out<<<1, 256, 0, stream>>>(sg1, c0, Wlin, blin, out);
}

// Round 6
// 83.700 us; speedup vs baseline: 1.5968x; 1.0034x over previous
//
#include <hip/hip_runtime.h>
#include <math.h>

#define LAG 100
#define HID 150

__device__ __forceinline__ float sigmoidf_(float x) {
    return 1.0f / (1.0f + expf(-x));
}

// ---------------- K1: layer0 gates + cell0 -> h1 ----------------
// 150 blocks x 256 threads. Block b's wave w computes gate row r = w*150 + b
// (all four gates of element b live in block b), then t==0 finishes cell0
// locally and publishes h1[b]. Weight/bias loads hoisted above the LDS
// staging so cold-HBM latency overlaps the barrier. fmaf order identical to
// the verified R5 kernel -> bitwise-equal output.
extern "C" __global__ __launch_bounds__(256, 1)
void k_gates0_cell0(const float* __restrict__ x,     // [100]
                    const float* __restrict__ h0,    // [2,150]
                    const float* __restrict__ c0,    // [2,150]
                    const float* __restrict__ Wih0,  // [600,100]
                    const float* __restrict__ Whh0,  // [600,150]
                    const float* __restrict__ bih0,  // [600]
                    const float* __restrict__ bhh0,  // [600]
                    float* __restrict__ h1ws)        // [150] out (ws)
{
    __shared__ float sv[LAG + HID];            // x ++ h0[layer0]
    __shared__ float g0s[4];
    const int t    = threadIdx.x;
    const int b    = blockIdx.x;               // element 0..149
    const int w    = t >> 6;                   // gate 0..3 (i,f,g,o)
    const int lane = t & 63;
    const int r    = w * HID + b;              // gate row 0..599

    // ---- hoisted cold loads (overlap staging + barrier) ----
    const float* __restrict__ wi = Wih0 + r * LAG;
    const float* __restrict__ wh = Whh0 + r * HID;
    const float wiv0 = wi[lane];
    const float wiv1 = (lane < LAG - 64) ? wi[lane + 64] : 0.0f;
    const float whv0 = wh[lane];
    const float whv1 = wh[lane + 64];
    const float whv2 = (lane < HID - 128) ? wh[lane + 128] : 0.0f;
    const float rb0  = bih0[r];
    const float rb1  = bhh0[r];
    const float c0a  = c0[b];

    if (t < LAG)            sv[t] = x[t];
    else if (t < LAG + HID) sv[t] = h0[t - LAG];
    __syncthreads();

    // ---- fmaf chain: identical order to R5 ----
    float acc = 0.0f;
    acc = fmaf(wiv0, sv[lane], acc);
    if (lane < LAG - 64)  acc = fmaf(wiv1, sv[lane + 64], acc);
    acc = fmaf(whv0, sv[LAG + lane], acc);
    acc = fmaf(whv1, sv[LAG + lane + 64], acc);
    if (lane < HID - 128) acc = fmaf(whv2, sv[LAG + lane + 128], acc);

    for (int off = 32; off > 0; off >>= 1)
        acc += __shfl_down(acc, off, 64);
    if (lane == 0) g0s[w] = acc + rb0 + rb1;
    __syncthreads();

    // ---- cell0 for element b (identical math/order to R5's K2 cell) ----
    if (t == 0) {
        float i = sigmoidf_(g0s[0]);
        float f = sigmoidf_(g0s[1]);
        float g = tanhf(g0s[2]);
        float o = sigmoidf_(g0s[3]);
        float c = fmaf(f, c0a, i * g);
        h1ws[b] = o * tanhf(c);
    }
}

// ---------------- K2: layer1 gates + cell1 -> h2 ----------------
// Same element-centric mapping; no redundant cell0, no transcendental
// pre-phase on the critical path. fmaf interleave identical to R5.
extern "C" __global__ __launch_bounds__(256, 1)
void k_gates1_cell1(const float* __restrict__ h1ws,  // [150] (ws, L2-hot)
                    const float* __restrict__ h0,    // [2,150]
                    const float* __restrict__ c0,    // [2,150]
                    const float* __restrict__ Wih1,  // [600,150]
                    const float* __restrict__ Whh1,  // [600,150]
                    const float* __restrict__ bih1,  // [600]
                    const float* __restrict__ bhh1,  // [600]
                    float* __restrict__ h2ws)        // [150] out (ws)
{
    __shared__ float sh1[HID];    // h1
    __shared__ float sh01[HID];   // h0[layer1]
    __shared__ float g1s[4];
    const int t    = threadIdx.x;
    const int b    = blockIdx.x;
    const int w    = t >> 6;
    const int lane = t & 63;
    const int r    = w * HID + b;

    // ---- hoisted cold loads ----
    const float* __restrict__ wi = Wih1 + r * HID;
    const float* __restrict__ wh = Whh1 + r * HID;
    const float wiv0 = wi[lane];
    const float wiv1 = wi[lane + 64];
    const float wiv2 = (lane < HID - 128) ? wi[lane + 128] : 0.0f;
    const float whv0 = wh[lane];
    const float whv1 = wh[lane + 64];
    const float whv2 = (lane < HID - 128) ? wh[lane + 128] : 0.0f;
    const float rb0  = bih1[r];
    const float rb1  = bhh1[r];
    const float c0b  = c0[HID + b];

    if (t < HID) {
        sh1[t]  = h1ws[t];
        sh01[t] = h0[HID + t];
    }
    __syncthreads();

    // ---- fmaf chain: identical interleaved order to R5 ----
    float acc = 0.0f;
    acc = fmaf(wiv0, sh1[lane], acc);
    acc = fmaf(whv0, sh01[lane], acc);
    acc = fmaf(wiv1, sh1[lane + 64], acc);
    acc = fmaf(whv1, sh01[lane + 64], acc);
    if (lane < HID - 128) {
        acc = fmaf(wiv2, sh1[lane + 128], acc);
        acc = fmaf(whv2, sh01[lane + 128], acc);
    }

    for (int off = 32; off > 0; off >>= 1)
        acc += __shfl_down(acc, off, 64);
    if (lane == 0) g1s[w] = acc + rb0 + rb1;
    __syncthreads();

    // ---- cell1 for element b (identical math/order to R5's K3 cell) ----
    if (t == 0) {
        float i = sigmoidf_(g1s[0]);
        float f = sigmoidf_(g1s[1]);
        float g = tanhf(g1s[2]);
        float o = sigmoidf_(g1s[3]);
        float c = fmaf(f, c0b, i * g);
        h2ws[b] = o * tanhf(c);
    }
}

// ---------------- K3: pure output dot (no transcendentals) ----------------
// Identical reduction tree to R5's K3; v-values are bitwise-equal since
// h2[t] = o*tanh(c) was computed with the same op order in K2.
extern "C" __global__ __launch_bounds__(256, 1)
void k_out(const float* __restrict__ h2ws,  // [150] (ws, L2-hot)
           const float* __restrict__ Wlin,  // [150]
           const float* __restrict__ blin,  // [1]
           float* __restrict__ out)         // [1]
{
    const int t = threadIdx.x;
    float v = 0.0f;
    if (t < HID) v = h2ws[t] * Wlin[t];
    for (int off = 32; off > 0; off >>= 1)
        v += __shfl_down(v, off, 64);

    __shared__ float wsum[4];
    if ((t & 63) == 0) wsum[t >> 6] = v;
    __syncthreads();
    if (t == 0)
        out[0] = wsum[0] + wsum[1] + wsum[2] + wsum[3] + blin[0];
}

extern "C" void kernel_launch(void* const* d_in, const int* in_sizes, int n_in,
                              void* d_out, int out_size, void* d_ws, size_t ws_size,
                              hipStream_t stream) {
    const float* x    = (const float*)d_in[0];
    const float* h0   = (const float*)d_in[1];
    const float* c0   = (const float*)d_in[2];
    const float* Wih0 = (const float*)d_in[3];
    const float* Whh0 = (const float*)d_in[4];
    const float* bih0 = (const float*)d_in[5];
    const float* bhh0 = (const float*)d_in[6];
    const float* Wih1 = (const float*)d_in[7];
    const float* Whh1 = (const float*)d_in[8];
    const float* bih1 = (const float*)d_in[9];
    const float* bhh1 = (const float*)d_in[10];
    const float* Wlin = (const float*)d_in[11];
    const float* blin = (const float*)d_in[12];
    float* out = (float*)d_out;

    float* h1ws = (float*)d_ws;         // [150]
    float* h2ws = h1ws + 256;           // [150]

    k_gates0_cell0<<<150, 256, 0, stream>>>(x, h0, c0, Wih0, Whh0, bih0, bhh0, h1ws);
    k_gates1_cell1<<<150, 256, 0, stream>>>(h1ws, h0, c0, Wih1, Whh1, bih1, bhh1, h2ws);
    k_out<<<1, 256, 0, stream>>>(h2ws, Wlin, blin, out);
}